// Round 6
// baseline (687.918 us; speedup 1.0000x reference)
//
#include <hip/hip_runtime.h>
#include <hip/hip_bf16.h>

// GridAttention restructured:
//   score_h(t) = r_h . x_t + off_h,   r_h = ((q Wq^T + bq)_h / sqrt(32)) Wk_h
//   attn_out   = (attn . x) @ N + b_eff,  N[(h,j),k] = sum_i Wv[h32+i,j] Wo[k,h32+i]
//   out        = q_pool + b_eff + attn.x @ N   (q path kept exact fp32)
// R2 design (4th submit; R3/R5 acquisition timeout, R4 container failure — never measured):
// XCD-bijective cell swizzle (FETCH 533->~280MB predicted), batched Ph0 loads,
// ILP'd Ph1 reduce chains, k_out K-split x4 + atomicAdd, q+BE folded into k_cell.

#define NCELL 4096

typedef float f32x4 __attribute__((ext_vector_type(4)));
typedef short s16x8 __attribute__((ext_vector_type(8)));

// workspace layout in float units
#define OFF_NT 0u          // bf16 [256 n][2048 k] -> 262144 float slots
#define OFF_BE 262144u     // f32 [256]
#define OFF_S 1310976u     // bf16 [4096][2048] -> 4194304 float slots
#define OFF_WQB 5505280u   // bf16 [256][256] -> 32768 float slots
#define OFF_WKB 5538048u   // bf16 [256][256] -> 32768 float slots
// total ws need: 5,570,816 floats = 21.25 MiB

__device__ __forceinline__ unsigned short bfrnd(float f) {
  unsigned u = __float_as_uint(f);
  u += 0x7fffu + ((u >> 16) & 1u);
  return (unsigned short)(u >> 16);
}
__device__ __forceinline__ float bflo(unsigned u) { return __uint_as_float(u << 16); }
__device__ __forceinline__ float bfhi(unsigned u) { return __uint_as_float(u & 0xffff0000u); }

// ---- prep: f32 -> bf16 copies of Wq, Wk ----
__global__ __launch_bounds__(256) void k_cvt(const float* __restrict__ Wq, const float* __restrict__ Wk,
                                             unsigned short* __restrict__ WQB, unsigned short* __restrict__ WKB) {
  const int i = blockIdx.x * 256 + threadIdx.x;
  {
    const float4 v = *reinterpret_cast<const float4*>(Wq + i * 4);
    const unsigned lo = (unsigned)bfrnd(v.x) | ((unsigned)bfrnd(v.y) << 16);
    const unsigned hi = (unsigned)bfrnd(v.z) | ((unsigned)bfrnd(v.w) << 16);
    *reinterpret_cast<uint2*>(WQB + i * 4) = make_uint2(lo, hi);
  }
  {
    const float4 v = *reinterpret_cast<const float4*>(Wk + i * 4);
    const unsigned lo = (unsigned)bfrnd(v.x) | ((unsigned)bfrnd(v.y) << 16);
    const unsigned hi = (unsigned)bfrnd(v.z) | ((unsigned)bfrnd(v.w) << 16);
    *reinterpret_cast<uint2*>(WKB + i * 4) = make_uint2(lo, hi);
  }
}

// ---- prep: NT[n][h*256+j] = sum_i Wv[h*32+i][j] * Wo[n][h*32+i]  (bf16) ----
__global__ __launch_bounds__(256) void k_nt(const float* __restrict__ Wv, const float* __restrict__ Wo,
                                            unsigned short* __restrict__ NT) {
  __shared__ float wo_s[32];
  const int n = blockIdx.x >> 3, h = blockIdx.x & 7;
  const int j = threadIdx.x;
  if (threadIdx.x < 32) wo_s[threadIdx.x] = Wo[n * 256 + h * 32 + threadIdx.x];
  __syncthreads();
  float acc = 0.f;
#pragma unroll
  for (int i = 0; i < 32; ++i) acc += Wv[(h * 32 + i) * 256 + j] * wo_s[i];
  NT[(size_t)n * 2048 + h * 256 + j] = bfrnd(acc);
}

// ---- prep: b_eff[k] = bo[k] + sum_i bv[i] * Wo[k][i]; block b -> k = b*4 + wave ----
__global__ __launch_bounds__(256) void k_beff(const float* __restrict__ bo, const float* __restrict__ bv,
                                              const float* __restrict__ Wo, float* __restrict__ BE) {
  const int w = threadIdx.x >> 6, l = threadIdx.x & 63;
  const int k = blockIdx.x * 4 + w;
  float acc = 0.f;
#pragma unroll
  for (int c = 0; c < 4; ++c) acc += bv[l + 64 * c] * Wo[k * 256 + l + 64 * c];
#pragma unroll
  for (int mk = 32; mk >= 1; mk >>= 1) acc += __shfl_xor(acc, mk);
  if (l == 0) BE[k] = acc + bo[k];
}

// ---- fused per-cell: pool + qp + r + scores + softmax + weighted sums ----
// also writes out[cell][:] = q + b_eff (fp32 residual backbone); k_out atomicAdds GEMM part.
__global__ __launch_bounds__(256, 3) void k_cell(
    const float* __restrict__ x,
    const unsigned short* __restrict__ WQB, const float* __restrict__ bq,
    const unsigned short* __restrict__ WKB, const float* __restrict__ bk,
    const float* __restrict__ BE,
    float* __restrict__ out, unsigned short* __restrict__ Sg) {
  // LDS: 36864 + 1024 + 1024 + 4224 + 9216 + 32 = 52,384 B -> 3 blocks/CU
  __shared__ __align__(16) unsigned short xb[256 * 72];  // bf16 x, [d][t], stride 72
  __shared__ __align__(16) float q_s[256];
  __shared__ __align__(16) float qp_s[256];
  __shared__ __align__(16) unsigned short r_bf[8 * 264];  // bf16 r, [h][d], stride 264
  __shared__ __align__(16) float R1[2304];  // alias: partial[4][64][9] -> attn[64][12]
  __shared__ float off_s[8];

  const int tid = threadIdx.x;
  // XCD-bijective chunked swizzle: orig blocks 8k..8k+7 land on XCDs 0..7; map so each
  // XCD owns 512 CONSECUTIVE cells -> ch-adjacent cells share 64B HBM lines within one L2.
  const int cell = ((blockIdx.x & 7) << 9) | (blockIdx.x >> 3);
  const int b = cell >> 10, cw = (cell >> 5) & 31, ch = cell & 31;
  const float* xp = x + (size_t)b * 16777216 + (size_t)cw * 2048 + (size_t)ch * 8;

  // Ph0: batch-issue ALL 16 global float4 loads, then pack/pool.
  const int i_row = (tid >> 1) & 7, half = tid & 1, d0 = tid >> 4;
  const float* tb = xp + (size_t)d0 * 65536 + i_row * 256 + half * 4;
  float4 v[16];
#pragma unroll
  for (int it = 0; it < 16; ++it)
    v[it] = *reinterpret_cast<const float4*>(tb + (size_t)it * 1048576);
  const int t0 = i_row * 8 + half * 4;
#pragma unroll
  for (int it = 0; it < 16; ++it) {
    const int d = it * 16 + d0;
    const unsigned lo = (unsigned)bfrnd(v[it].x) | ((unsigned)bfrnd(v[it].y) << 16);
    const unsigned hi = (unsigned)bfrnd(v[it].z) | ((unsigned)bfrnd(v[it].w) << 16);
    *reinterpret_cast<uint2*>(&xb[d * 72 + t0]) = make_uint2(lo, hi);
    float ps = (v[it].x + v[it].y) + (v[it].z + v[it].w);
    ps += __shfl_xor(ps, 1);
    ps += __shfl_xor(ps, 2);
    ps += __shfl_xor(ps, 4);
    ps += __shfl_xor(ps, 8);
    if ((tid & 15) == 0) q_s[d] = ps * (1.0f / 64.0f);
  }
  __syncthreads();

  // residual backbone: out = q + b_eff (exact fp32), coalesced
  out[(size_t)cell * 256 + tid] = q_s[tid] + BE[tid];

  // Ph1: qp'[i] = (q . Wq[i,:] + bq[i]) / sqrt(32); j-split over 32 lanes,
  // 4 interleaved shfl-reduce chains for ILP.
  {
    const int io = tid >> 5, jl = tid & 31;
    float qr[8];
    *reinterpret_cast<float4*>(qr) = *reinterpret_cast<const float4*>(&q_s[jl * 8]);
    *reinterpret_cast<float4*>(qr + 4) = *reinterpret_cast<const float4*>(&q_s[jl * 8 + 4]);
#pragma unroll
    for (int rb = 0; rb < 8; ++rb) {
      float acc[4];
#pragma unroll
      for (int rr = 0; rr < 4; ++rr) {
        const int i = (rb * 4 + rr) * 8 + io;
        const uint4 wv = *reinterpret_cast<const uint4*>(WQB + i * 256 + jl * 8);
        acc[rr] = bflo(wv.x) * qr[0] + bfhi(wv.x) * qr[1] + bflo(wv.y) * qr[2] + bfhi(wv.y) * qr[3] +
                  bflo(wv.z) * qr[4] + bfhi(wv.z) * qr[5] + bflo(wv.w) * qr[6] + bfhi(wv.w) * qr[7];
      }
#pragma unroll
      for (int mk = 16; mk >= 1; mk >>= 1) {
#pragma unroll
        for (int rr = 0; rr < 4; ++rr) acc[rr] += __shfl_xor(acc[rr], mk);
      }
      if (jl == 0) {
#pragma unroll
        for (int rr = 0; rr < 4; ++rr) {
          const int i = (rb * 4 + rr) * 8 + io;
          qp_s[i] = (acc[rr] + bq[i]) * 0.17677669529663689f;
        }
      }
    }
  }
  __syncthreads();

  // Ph2: r[h][j] = sum_i qp'[h*32+i] * Wk[h*32+i][j] -> bf16 LDS ; off_h = qp'_h . bk_h
  {
    const int hw = tid >> 6;         // wave -> heads hw*2, hw*2+1
    const int j0 = (tid & 63) * 4;   // 4 consecutive j per lane
#pragma unroll
    for (int hh = 0; hh < 2; ++hh) {
      const int h = hw * 2 + hh;
      float a0 = 0.f, a1 = 0.f, a2 = 0.f, a3 = 0.f;
#pragma unroll
      for (int i = 0; i < 32; ++i) {
        const float s = qp_s[h * 32 + i];
        const uint2 wv = *reinterpret_cast<const uint2*>(WKB + (h * 32 + i) * 256 + j0);
        a0 += s * bflo(wv.x);
        a1 += s * bfhi(wv.x);
        a2 += s * bflo(wv.y);
        a3 += s * bfhi(wv.y);
      }
      const unsigned lo = (unsigned)bfrnd(a0) | ((unsigned)bfrnd(a1) << 16);
      const unsigned hi = (unsigned)bfrnd(a2) | ((unsigned)bfrnd(a3) << 16);
      *reinterpret_cast<uint2*>(&r_bf[h * 264 + j0]) = make_uint2(lo, hi);
    }
    if (tid < 8) {
      float o = 0.f;
      for (int i = 0; i < 32; ++i) o += qp_s[tid * 32 + i] * bk[tid * 32 + i];
      off_s[tid] = o;
    }
  }
  __syncthreads();

  // Ph3: score partials over d-quarters: partial[p][t][h] (stride-9 = conflict-free)
  {
    const int t = tid & 63, p = tid >> 6;
    float xr[64];
#pragma unroll
    for (int dd = 0; dd < 64; ++dd) {
      const unsigned vv = xb[(p * 64 + dd) * 72 + t];
      xr[dd] = __uint_as_float(vv << 16);
    }
#pragma unroll
    for (int h = 0; h < 8; ++h) {
      float acc = 0.f;
#pragma unroll
      for (int dc = 0; dc < 8; ++dc) {
        const uint4 rv = *reinterpret_cast<const uint4*>(&r_bf[h * 264 + p * 64 + dc * 8]);
        acc += bflo(rv.x) * xr[dc * 8 + 0] + bfhi(rv.x) * xr[dc * 8 + 1] +
               bflo(rv.y) * xr[dc * 8 + 2] + bfhi(rv.y) * xr[dc * 8 + 3] +
               bflo(rv.z) * xr[dc * 8 + 4] + bfhi(rv.z) * xr[dc * 8 + 5] +
               bflo(rv.w) * xr[dc * 8 + 6] + bfhi(rv.w) * xr[dc * 8 + 7];
      }
      R1[p * 576 + t * 9 + h] = acc;
    }
  }
  __syncthreads();

  // Ph4: softmax; wave w handles h = w, w+4; lane t = token -> full-wave shfl reduce
  {
    const int w = tid >> 6, t = tid & 63;
    float av[2];
#pragma unroll
    for (int hi = 0; hi < 2; ++hi) {
      const int h = w + hi * 4;
      const float vv = R1[0 * 576 + t * 9 + h] + R1[1 * 576 + t * 9 + h] +
                       R1[2 * 576 + t * 9 + h] + R1[3 * 576 + t * 9 + h] + off_s[h];
      float m = vv;
#pragma unroll
      for (int mk = 32; mk >= 1; mk >>= 1) m = fmaxf(m, __shfl_xor(m, mk));
      const float e = __expf(vv - m);
      float s = e;
#pragma unroll
      for (int mk = 32; mk >= 1; mk >>= 1) s += __shfl_xor(s, mk);
      av[hi] = e / s;
    }
    __syncthreads();  // all partial reads done before aliased attn writes
    R1[t * 12 + w] = av[0];
    R1[t * 12 + w + 4] = av[1];
  }
  __syncthreads();

  // Ph5: S[h][d] = sum_t attn[h][t] * x[t][d]  -> bf16 global
  {
    const int d = tid;
    float acc[8] = {0, 0, 0, 0, 0, 0, 0, 0};
#pragma unroll
    for (int tc = 0; tc < 8; ++tc) {
      const uint4 xv = *reinterpret_cast<const uint4*>(&xb[d * 72 + tc * 8]);
      const float xf[8] = {bflo(xv.x), bfhi(xv.x), bflo(xv.y), bfhi(xv.y),
                           bflo(xv.z), bfhi(xv.z), bflo(xv.w), bfhi(xv.w)};
#pragma unroll
      for (int k = 0; k < 8; ++k) {
        const int t = tc * 8 + k;
        const float4 aA = *reinterpret_cast<const float4*>(&R1[t * 12]);
        const float4 aB = *reinterpret_cast<const float4*>(&R1[t * 12 + 4]);
        acc[0] += aA.x * xf[k]; acc[1] += aA.y * xf[k];
        acc[2] += aA.z * xf[k]; acc[3] += aA.w * xf[k];
        acc[4] += aB.x * xf[k]; acc[5] += aB.y * xf[k];
        acc[6] += aB.z * xf[k]; acc[7] += aB.w * xf[k];
      }
    }
#pragma unroll
    for (int h = 0; h < 8; ++h)
      Sg[(size_t)cell * 2048 + h * 256 + d] = bfrnd(acc[h]);
  }
}

// ---- out += S @ N  (bf16 MFMA, K-split x4, fp32 atomic epilogue) ----
__global__ __launch_bounds__(256, 4) void k_out(
    const unsigned short* __restrict__ Sg, const unsigned short* __restrict__ NT,
    float* __restrict__ out) {
  __shared__ __align__(16) unsigned short As[64 * 72];
  __shared__ __align__(16) unsigned short Bs[64 * 72];
  const int tid = threadIdx.x;
  const int tile = blockIdx.x >> 2, ks = blockIdx.x & 3;
  const int m0 = (tile >> 2) * 64, n0 = (tile & 3) * 64;
  const int w = tid >> 6, l = tid & 63;
  const int wm = (w & 1) * 32, wn = (w >> 1) * 32;
  const int lr = l & 15, lq = l >> 4;

  f32x4 acc[2][2];
#pragma unroll
  for (int a = 0; a < 2; ++a)
#pragma unroll
    for (int c = 0; c < 2; ++c) acc[a][c] = (f32x4){0.f, 0.f, 0.f, 0.f};

  const int srow = tid >> 2, sseg = tid & 3;
  const size_t arow = (size_t)(m0 + srow) * 2048 + sseg * 16;
  const size_t brow = (size_t)(n0 + srow) * 2048 + sseg * 16;
  const int kbase = ks * 512;

  uint4 a0v = *reinterpret_cast<const uint4*>(&Sg[arow + kbase]);
  uint4 a1v = *reinterpret_cast<const uint4*>(&Sg[arow + kbase + 8]);
  uint4 b0v = *reinterpret_cast<const uint4*>(&NT[brow + kbase]);
  uint4 b1v = *reinterpret_cast<const uint4*>(&NT[brow + kbase + 8]);

  for (int kt = 0; kt < 8; ++kt) {
    __syncthreads();  // prior MFMA frag reads complete
    *reinterpret_cast<uint4*>(&As[srow * 72 + sseg * 16]) = a0v;
    *reinterpret_cast<uint4*>(&As[srow * 72 + sseg * 16 + 8]) = a1v;
    *reinterpret_cast<uint4*>(&Bs[srow * 72 + sseg * 16]) = b0v;
    *reinterpret_cast<uint4*>(&Bs[srow * 72 + sseg * 16 + 8]) = b1v;
    __syncthreads();
    if (kt < 7) {  // prefetch next K-tile; overlaps with MFMA below
      const int kn = kbase + (kt + 1) * 64;
      a0v = *reinterpret_cast<const uint4*>(&Sg[arow + kn]);
      a1v = *reinterpret_cast<const uint4*>(&Sg[arow + kn + 8]);
      b0v = *reinterpret_cast<const uint4*>(&NT[brow + kn]);
      b1v = *reinterpret_cast<const uint4*>(&NT[brow + kn + 8]);
    }
#pragma unroll
    for (int s = 0; s < 2; ++s) {
      s16x8 af[2], bfr[2];
#pragma unroll
      for (int a = 0; a < 2; ++a)
        af[a] = *reinterpret_cast<const s16x8*>(&As[(wm + a * 16 + lr) * 72 + s * 32 + lq * 8]);
#pragma unroll
      for (int c = 0; c < 2; ++c)
        bfr[c] = *reinterpret_cast<const s16x8*>(&Bs[(wn + c * 16 + lr) * 72 + s * 32 + lq * 8]);
#pragma unroll
      for (int a = 0; a < 2; ++a)
#pragma unroll
        for (int c = 0; c < 2; ++c)
          acc[a][c] = __builtin_amdgcn_mfma_f32_16x16x32_bf16(af[a], bfr[c], acc[a][c], 0, 0, 0);
    }
  }
#pragma unroll
  for (int a = 0; a < 2; ++a) {
#pragma unroll
    for (int c = 0; c < 2; ++c) {
      const int col = n0 + wn + c * 16 + lr;
#pragma unroll
      for (int rr = 0; rr < 4; ++rr) {
        const int row = m0 + wm + a * 16 + lq * 4 + rr;
        atomicAdd(&out[(size_t)row * 256 + col], acc[a][c][rr]);
      }
    }
  }
}

extern "C" void kernel_launch(void* const* d_in, const int* in_sizes, int n_in,
                              void* d_out, int out_size, void* d_ws, size_t ws_size,
                              hipStream_t stream) {
  const float* x = (const float*)d_in[0];
  const float* Wq = (const float*)d_in[1];
  const float* bq = (const float*)d_in[2];
  const float* Wk = (const float*)d_in[3];
  const float* bk = (const float*)d_in[4];
  const float* Wv = (const float*)d_in[5];
  const float* bv = (const float*)d_in[6];
  const float* Wo = (const float*)d_in[7];
  const float* bo = (const float*)d_in[8];
  float* ws = (float*)d_ws;
  unsigned short* NT = (unsigned short*)(ws + OFF_NT);
  float* BE = ws + OFF_BE;
  unsigned short* Sg = (unsigned short*)(ws + OFF_S);
  unsigned short* WQB = (unsigned short*)(ws + OFF_WQB);
  unsigned short* WKB = (unsigned short*)(ws + OFF_WKB);
  float* out = (float*)d_out;

  hipLaunchKernelGGL(k_cvt, dim3(64), dim3(256), 0, stream, Wq, Wk, WQB, WKB);
  hipLaunchKernelGGL(k_nt, dim3(2048), dim3(256), 0, stream, Wv, Wo, NT);
  hipLaunchKernelGGL(k_beff, dim3(64), dim3(256), 0, stream, bo, bv, Wo, BE);
  hipLaunchKernelGGL(k_cell, dim3(NCELL), dim3(256), 0, stream, x, WQB, bq, WKB, bk, BE, out, Sg);
  hipLaunchKernelGGL(k_out, dim3(1024), dim3(256), 0, stream, Sg, NT, out);
}

// Round 7
// 576.368 us; speedup vs baseline: 1.1935x; 1.1935x over previous
//
#include <hip/hip_runtime.h>
#include <hip/hip_bf16.h>

// GridAttention restructured:
//   score_h(t) = r_h . x_t + off_h,   r_h = ((q Wq^T + bq)_h / sqrt(32)) Wk_h
//   attn_out   = (attn . x) @ N + b_eff,  N[(h,j),k] = sum_i Wv[h32+i,j] Wo[k,h32+i]
//   out        = q_pool + b_eff + attn.x @ N   (q path fp32)
// R6: k_cell staging via global_load_lds (async DMA, no VGPR -> no spill; R2's v[16]
// spilled to scratch: VGPR 108->84, WRITE 20->495MB). x kept fp32 in LDS [256][64];
// pool = per-thread LDS row sum (no shfl); Ph3 reads fp32 b32 conflict-free.
// Swizzle kept (FETCH 533->454 measured). k_out unchanged.

#define NCELL 4096

typedef float f32x4 __attribute__((ext_vector_type(4)));
typedef short s16x8 __attribute__((ext_vector_type(8)));

// workspace layout in float units
#define OFF_NT 0u          // bf16 [256 n][2048 k] -> 262144 float slots
#define OFF_BE 262144u     // f32 [256]
#define OFF_S 1310976u     // bf16 [4096][2048] -> 4194304 float slots
#define OFF_WQB 5505280u   // bf16 [256][256] -> 32768 float slots
#define OFF_WKB 5538048u   // bf16 [256][256] -> 32768 float slots

__device__ __forceinline__ unsigned short bfrnd(float f) {
  unsigned u = __float_as_uint(f);
  u += 0x7fffu + ((u >> 16) & 1u);
  return (unsigned short)(u >> 16);
}
__device__ __forceinline__ float bflo(unsigned u) { return __uint_as_float(u << 16); }
__device__ __forceinline__ float bfhi(unsigned u) { return __uint_as_float(u & 0xffff0000u); }

__device__ __forceinline__ void gl_lds16(const float* g, float* l) {
  __builtin_amdgcn_global_load_lds(
      (const __attribute__((address_space(1))) unsigned int*)g,
      (__attribute__((address_space(3))) unsigned int*)l, 16, 0, 0);
}

// ---- prep: f32 -> bf16 copies of Wq, Wk ----
__global__ __launch_bounds__(256) void k_cvt(const float* __restrict__ Wq, const float* __restrict__ Wk,
                                             unsigned short* __restrict__ WQB, unsigned short* __restrict__ WKB) {
  const int i = blockIdx.x * 256 + threadIdx.x;
  {
    const float4 v = *reinterpret_cast<const float4*>(Wq + i * 4);
    const unsigned lo = (unsigned)bfrnd(v.x) | ((unsigned)bfrnd(v.y) << 16);
    const unsigned hi = (unsigned)bfrnd(v.z) | ((unsigned)bfrnd(v.w) << 16);
    *reinterpret_cast<uint2*>(WQB + i * 4) = make_uint2(lo, hi);
  }
  {
    const float4 v = *reinterpret_cast<const float4*>(Wk + i * 4);
    const unsigned lo = (unsigned)bfrnd(v.x) | ((unsigned)bfrnd(v.y) << 16);
    const unsigned hi = (unsigned)bfrnd(v.z) | ((unsigned)bfrnd(v.w) << 16);
    *reinterpret_cast<uint2*>(WKB + i * 4) = make_uint2(lo, hi);
  }
}

// ---- prep: NT[n][h*256+j] = sum_i Wv[h*32+i][j] * Wo[n][h*32+i]  (bf16) ----
__global__ __launch_bounds__(256) void k_nt(const float* __restrict__ Wv, const float* __restrict__ Wo,
                                            unsigned short* __restrict__ NT) {
  __shared__ float wo_s[32];
  const int n = blockIdx.x >> 3, h = blockIdx.x & 7;
  const int j = threadIdx.x;
  if (threadIdx.x < 32) wo_s[threadIdx.x] = Wo[n * 256 + h * 32 + threadIdx.x];
  __syncthreads();
  float acc = 0.f;
#pragma unroll
  for (int i = 0; i < 32; ++i) acc += Wv[(h * 32 + i) * 256 + j] * wo_s[i];
  NT[(size_t)n * 2048 + h * 256 + j] = bfrnd(acc);
}

// ---- prep: b_eff[k] = bo[k] + sum_i bv[i] * Wo[k][i]; block b -> k = b*4 + wave ----
__global__ __launch_bounds__(256) void k_beff(const float* __restrict__ bo, const float* __restrict__ bv,
                                              const float* __restrict__ Wo, float* __restrict__ BE) {
  const int w = threadIdx.x >> 6, l = threadIdx.x & 63;
  const int k = blockIdx.x * 4 + w;
  float acc = 0.f;
#pragma unroll
  for (int c = 0; c < 4; ++c) acc += bv[l + 64 * c] * Wo[k * 256 + l + 64 * c];
#pragma unroll
  for (int mk = 32; mk >= 1; mk >>= 1) acc += __shfl_xor(acc, mk);
  if (l == 0) BE[k] = acc + bo[k];
}

// ---- fused per-cell: async stage + pool + qp + r + scores + softmax + weighted sums ----
__global__ __launch_bounds__(256, 2) void k_cell(
    const float* __restrict__ x,
    const unsigned short* __restrict__ WQB, const float* __restrict__ bq,
    const unsigned short* __restrict__ WKB, const float* __restrict__ bk,
    const float* __restrict__ BE,
    float* __restrict__ out, unsigned short* __restrict__ Sg) {
  // LDS: 65536 + 1024 + 1024 + 4224 + 9216 + 32 = 81,056 B -> 2 blocks/CU (162,112 <= 163,840)
  __shared__ __align__(16) float xb[256 * 64];   // fp32 x, [d][t=64], linear (gl_lds dest)
  __shared__ __align__(16) float q_s[256];
  __shared__ __align__(16) float qp_s[256];
  __shared__ __align__(16) unsigned short r_bf[8 * 264];  // bf16 r, [h][d], stride 264
  __shared__ __align__(16) float R1[2304];  // alias: partial[4][64][9] -> attn[64][12]
  __shared__ float off_s[8];

  const int tid = threadIdx.x;
  // XCD-bijective chunked swizzle: each XCD owns 512 consecutive cells -> ch-neighbors
  // (which split 64B HBM lines) co-resident in one L2.
  const int cell = ((blockIdx.x & 7) << 9) | (blockIdx.x >> 3);
  const int b = cell >> 10, cw = (cell >> 5) & 31, ch = cell & 31;
  const float* xp = x + (size_t)b * 16777216 + (size_t)cw * 2048 + (size_t)ch * 8;

  // Ph0: async DMA x -> LDS fp32 [d][t]. Wave w, iter k stages rows d = w*64+k*4 .. +3.
  // HW semantics: LDS dest = wave-uniform base + lane*16B; lane l -> d=base+(l>>4), t=(l&15)*4.
  {
    const int w = tid >> 6, l = tid & 63;
    const int dl = l >> 4;                 // row within 4-row group
    const int m = l & 15;                  // t quarter: t = m*4
    const int i_row = m >> 1, j0 = (m & 1) * 4;  // token t = i_row*8 + j0 (+0..3)
    const float* gs0 = xp + (size_t)dl * 65536 + i_row * 256 + j0;
#pragma unroll
    for (int k = 0; k < 16; ++k) {
      const int dbase = w * 64 + k * 4;
      gl_lds16(gs0 + (size_t)dbase * 65536, &xb[dbase * 64 + l * 4]);
    }
  }
  __syncthreads();  // compiler drains vmcnt before barrier

  // Pool: thread tid owns row d=tid; sum 64 floats via rotated b128 chunks (8-pass LDS).
  {
    f32x4 s4 = {0.f, 0.f, 0.f, 0.f};
#pragma unroll
    for (int c = 0; c < 16; ++c) {
      const int chunk = (tid + c) & 15;
      s4 += *reinterpret_cast<const f32x4*>(&xb[tid * 64 + chunk * 4]);
    }
    const float qv = (s4.x + s4.y + s4.z + s4.w) * (1.0f / 64.0f);
    q_s[tid] = qv;
    out[(size_t)cell * 256 + tid] = qv + BE[tid];  // fp32 residual backbone
  }
  __syncthreads();

  // Ph1: qp'[i] = (q . Wq[i,:] + bq[i]) / sqrt(32); j-split over 32 lanes, 4 ILP chains.
  {
    const int io = tid >> 5, jl = tid & 31;
    float qr[8];
    *reinterpret_cast<float4*>(qr) = *reinterpret_cast<const float4*>(&q_s[jl * 8]);
    *reinterpret_cast<float4*>(qr + 4) = *reinterpret_cast<const float4*>(&q_s[jl * 8 + 4]);
#pragma unroll
    for (int rb = 0; rb < 8; ++rb) {
      float acc[4];
#pragma unroll
      for (int rr = 0; rr < 4; ++rr) {
        const int i = (rb * 4 + rr) * 8 + io;
        const uint4 wv = *reinterpret_cast<const uint4*>(WQB + i * 256 + jl * 8);
        acc[rr] = bflo(wv.x) * qr[0] + bfhi(wv.x) * qr[1] + bflo(wv.y) * qr[2] + bfhi(wv.y) * qr[3] +
                  bflo(wv.z) * qr[4] + bfhi(wv.z) * qr[5] + bflo(wv.w) * qr[6] + bfhi(wv.w) * qr[7];
      }
#pragma unroll
      for (int mk = 16; mk >= 1; mk >>= 1) {
#pragma unroll
        for (int rr = 0; rr < 4; ++rr) acc[rr] += __shfl_xor(acc[rr], mk);
      }
      if (jl == 0) {
#pragma unroll
        for (int rr = 0; rr < 4; ++rr) {
          const int i = (rb * 4 + rr) * 8 + io;
          qp_s[i] = (acc[rr] + bq[i]) * 0.17677669529663689f;
        }
      }
    }
  }
  __syncthreads();

  // Ph2: r[h][j] = sum_i qp'[h*32+i] * Wk[h*32+i][j] -> bf16 LDS ; off_h = qp'_h . bk_h
  {
    const int hw = tid >> 6;
    const int j0 = (tid & 63) * 4;
#pragma unroll
    for (int hh = 0; hh < 2; ++hh) {
      const int h = hw * 2 + hh;
      float a0 = 0.f, a1 = 0.f, a2 = 0.f, a3 = 0.f;
#pragma unroll
      for (int i = 0; i < 32; ++i) {
        const float s = qp_s[h * 32 + i];
        const uint2 wv = *reinterpret_cast<const uint2*>(WKB + (h * 32 + i) * 256 + j0);
        a0 += s * bflo(wv.x);
        a1 += s * bfhi(wv.x);
        a2 += s * bflo(wv.y);
        a3 += s * bfhi(wv.y);
      }
      const unsigned lo = (unsigned)bfrnd(a0) | ((unsigned)bfrnd(a1) << 16);
      const unsigned hi = (unsigned)bfrnd(a2) | ((unsigned)bfrnd(a3) << 16);
      *reinterpret_cast<uint2*>(&r_bf[h * 264 + j0]) = make_uint2(lo, hi);
    }
    if (tid < 8) {
      float o = 0.f;
      for (int i = 0; i < 32; ++i) o += qp_s[tid * 32 + i] * bk[tid * 32 + i];
      off_s[tid] = o;
    }
  }
  __syncthreads();

  // Ph3: score partials over d-quarters: partial[p][t][h]; fp32 x reads bank=t%32 (2-way=free)
  {
    const int t = tid & 63, p = tid >> 6;
    float xr[64];
#pragma unroll
    for (int dd = 0; dd < 64; ++dd) xr[dd] = xb[(p * 64 + dd) * 64 + t];
#pragma unroll
    for (int h = 0; h < 8; ++h) {
      float acc = 0.f;
#pragma unroll
      for (int dc = 0; dc < 8; ++dc) {
        const uint4 rv = *reinterpret_cast<const uint4*>(&r_bf[h * 264 + p * 64 + dc * 8]);
        acc += bflo(rv.x) * xr[dc * 8 + 0] + bfhi(rv.x) * xr[dc * 8 + 1] +
               bflo(rv.y) * xr[dc * 8 + 2] + bfhi(rv.y) * xr[dc * 8 + 3] +
               bflo(rv.z) * xr[dc * 8 + 4] + bfhi(rv.z) * xr[dc * 8 + 5] +
               bflo(rv.w) * xr[dc * 8 + 6] + bfhi(rv.w) * xr[dc * 8 + 7];
      }
      R1[p * 576 + t * 9 + h] = acc;
    }
  }
  __syncthreads();

  // Ph4: softmax; wave w handles h = w, w+4; lane t = token -> full-wave shfl reduce
  {
    const int w = tid >> 6, t = tid & 63;
    float av[2];
#pragma unroll
    for (int hi = 0; hi < 2; ++hi) {
      const int h = w + hi * 4;
      const float vv = R1[0 * 576 + t * 9 + h] + R1[1 * 576 + t * 9 + h] +
                       R1[2 * 576 + t * 9 + h] + R1[3 * 576 + t * 9 + h] + off_s[h];
      float m = vv;
#pragma unroll
      for (int mk = 32; mk >= 1; mk >>= 1) m = fmaxf(m, __shfl_xor(m, mk));
      const float e = __expf(vv - m);
      float s = e;
#pragma unroll
      for (int mk = 32; mk >= 1; mk >>= 1) s += __shfl_xor(s, mk);
      av[hi] = e / s;
    }
    __syncthreads();  // all partial reads done before aliased attn writes
    R1[t * 12 + w] = av[0];
    R1[t * 12 + w + 4] = av[1];
  }
  __syncthreads();

  // Ph5: S[h][d] = sum_t attn[h][t] * x[t][d]  -> bf16 global (rotated chunks, fp32 x)
  {
    const int d = tid;
    float acc[8] = {0, 0, 0, 0, 0, 0, 0, 0};
#pragma unroll
    for (int tc = 0; tc < 16; ++tc) {
      const int chunk = (d + tc) & 15;
      const f32x4 xv = *reinterpret_cast<const f32x4*>(&xb[d * 64 + chunk * 4]);
#pragma unroll
      for (int k = 0; k < 4; ++k) {
        const int t = chunk * 4 + k;
        const float xf = xv[k];
        const float4 aA = *reinterpret_cast<const float4*>(&R1[t * 12]);
        const float4 aB = *reinterpret_cast<const float4*>(&R1[t * 12 + 4]);
        acc[0] += aA.x * xf; acc[1] += aA.y * xf;
        acc[2] += aA.z * xf; acc[3] += aA.w * xf;
        acc[4] += aB.x * xf; acc[5] += aB.y * xf;
        acc[6] += aB.z * xf; acc[7] += aB.w * xf;
      }
    }
#pragma unroll
    for (int h = 0; h < 8; ++h)
      Sg[(size_t)cell * 2048 + h * 256 + d] = bfrnd(acc[h]);
  }
}

// ---- out += S @ N  (bf16 MFMA, K-split x4, fp32 atomic epilogue) ----
__global__ __launch_bounds__(256, 4) void k_out(
    const unsigned short* __restrict__ Sg, const unsigned short* __restrict__ NT,
    float* __restrict__ out) {
  __shared__ __align__(16) unsigned short As[64 * 72];
  __shared__ __align__(16) unsigned short Bs[64 * 72];
  const int tid = threadIdx.x;
  const int tile = blockIdx.x >> 2, ks = blockIdx.x & 3;
  const int m0 = (tile >> 2) * 64, n0 = (tile & 3) * 64;
  const int w = tid >> 6, l = tid & 63;
  const int wm = (w & 1) * 32, wn = (w >> 1) * 32;
  const int lr = l & 15, lq = l >> 4;

  f32x4 acc[2][2];
#pragma unroll
  for (int a = 0; a < 2; ++a)
#pragma unroll
    for (int c = 0; c < 2; ++c) acc[a][c] = (f32x4){0.f, 0.f, 0.f, 0.f};

  const int srow = tid >> 2, sseg = tid & 3;
  const size_t arow = (size_t)(m0 + srow) * 2048 + sseg * 16;
  const size_t brow = (size_t)(n0 + srow) * 2048 + sseg * 16;
  const int kbase = ks * 512;

  uint4 a0v = *reinterpret_cast<const uint4*>(&Sg[arow + kbase]);
  uint4 a1v = *reinterpret_cast<const uint4*>(&Sg[arow + kbase + 8]);
  uint4 b0v = *reinterpret_cast<const uint4*>(&NT[brow + kbase]);
  uint4 b1v = *reinterpret_cast<const uint4*>(&NT[brow + kbase + 8]);

  for (int kt = 0; kt < 8; ++kt) {
    __syncthreads();  // prior MFMA frag reads complete
    *reinterpret_cast<uint4*>(&As[srow * 72 + sseg * 16]) = a0v;
    *reinterpret_cast<uint4*>(&As[srow * 72 + sseg * 16 + 8]) = a1v;
    *reinterpret_cast<uint4*>(&Bs[srow * 72 + sseg * 16]) = b0v;
    *reinterpret_cast<uint4*>(&Bs[srow * 72 + sseg * 16 + 8]) = b1v;
    __syncthreads();
    if (kt < 7) {  // prefetch next K-tile; overlaps with MFMA below
      const int kn = kbase + (kt + 1) * 64;
      a0v = *reinterpret_cast<const uint4*>(&Sg[arow + kn]);
      a1v = *reinterpret_cast<const uint4*>(&Sg[arow + kn + 8]);
      b0v = *reinterpret_cast<const uint4*>(&NT[brow + kn]);
      b1v = *reinterpret_cast<const uint4*>(&NT[brow + kn + 8]);
    }
#pragma unroll
    for (int s = 0; s < 2; ++s) {
      s16x8 af[2], bfr[2];
#pragma unroll
      for (int a = 0; a < 2; ++a)
        af[a] = *reinterpret_cast<const s16x8*>(&As[(wm + a * 16 + lr) * 72 + s * 32 + lq * 8]);
#pragma unroll
      for (int c = 0; c < 2; ++c)
        bfr[c] = *reinterpret_cast<const s16x8*>(&Bs[(wn + c * 16 + lr) * 72 + s * 32 + lq * 8]);
#pragma unroll
      for (int a = 0; a < 2; ++a)
#pragma unroll
        for (int c = 0; c < 2; ++c)
          acc[a][c] = __builtin_amdgcn_mfma_f32_16x16x32_bf16(af[a], bfr[c], acc[a][c], 0, 0, 0);
    }
  }
#pragma unroll
  for (int a = 0; a < 2; ++a) {
#pragma unroll
    for (int c = 0; c < 2; ++c) {
      const int col = n0 + wn + c * 16 + lr;
#pragma unroll
      for (int rr = 0; rr < 4; ++rr) {
        const int row = m0 + wm + a * 16 + lq * 4 + rr;
        atomicAdd(&out[(size_t)row * 256 + col], acc[a][c][rr]);
      }
    }
  }
}

extern "C" void kernel_launch(void* const* d_in, const int* in_sizes, int n_in,
                              void* d_out, int out_size, void* d_ws, size_t ws_size,
                              hipStream_t stream) {
  const float* x = (const float*)d_in[0];
  const float* Wq = (const float*)d_in[1];
  const float* bq = (const float*)d_in[2];
  const float* Wk = (const float*)d_in[3];
  const float* bk = (const float*)d_in[4];
  const float* Wv = (const float*)d_in[5];
  const float* bv = (const float*)d_in[6];
  const float* Wo = (const float*)d_in[7];
  const float* bo = (const float*)d_in[8];
  float* ws = (float*)d_ws;
  unsigned short* NT = (unsigned short*)(ws + OFF_NT);
  float* BE = ws + OFF_BE;
  unsigned short* Sg = (unsigned short*)(ws + OFF_S);
  unsigned short* WQB = (unsigned short*)(ws + OFF_WQB);
  unsigned short* WKB = (unsigned short*)(ws + OFF_WKB);
  float* out = (float*)d_out;

  hipLaunchKernelGGL(k_cvt, dim3(64), dim3(256), 0, stream, Wq, Wk, WQB, WKB);
  hipLaunchKernelGGL(k_nt, dim3(2048), dim3(256), 0, stream, Wv, Wo, NT);
  hipLaunchKernelGGL(k_beff, dim3(64), dim3(256), 0, stream, bo, bv, Wo, BE);
  hipLaunchKernelGGL(k_cell, dim3(NCELL), dim3(256), 0, stream, x, WQB, bq, WKB, bk, BE, out, Sg);
  hipLaunchKernelGGL(k_out, dim3(1024), dim3(256), 0, stream, Sg, NT, out);
}